// Round 1
// baseline (759.193 us; speedup 1.0000x reference)
//
#include <hip/hip_runtime.h>
#include <cstdint>
#include <cstddef>

// Problem constants
constexpr int kH = 1024;
constexpr int kB = 128;
constexpr int kS = 256;
constexpr int kV = 32000;

typedef __attribute__((ext_vector_type(4))) float f32x4;
typedef __attribute__((ext_vector_type(8))) __bf16 bf16x8;
typedef __attribute__((ext_vector_type(8))) short short8;

__device__ __forceinline__ unsigned short f2bf_bits(float f) {
  unsigned u = __builtin_bit_cast(unsigned, f);
  u += 0x7FFFu + ((u >> 16) & 1u);   // round-to-nearest-even
  return (unsigned short)(u >> 16);
}

// ---------------------------------------------------------------------------
// Generic M=128 GEMM:  C[128,N] = A[128,K] @ W[N,K]^T + bias  (bf16 MFMA)
// Optional row indirection on A (embedding gather), optional second A matrix
// for k >= ksplit (concat of h1 and context). blockIdx.y selects pair 0/1 so
// the two GRU GEMMs (gi, gh) run in one launch.
// ---------------------------------------------------------------------------
struct GPair {
  const float* A;      // [128, lda0] rows (via rows[] if non-null)
  const int* rows;     // optional row indirection for A
  const float* A1;     // optional second A, used for k >= ksplit
  const float* W;      // [N, K] row-major
  const float* bias;   // [N]
  float* C;            // [128, N] row-major
};

template <int BN, int WAVES_M, int WAVES_N, bool TANH>
__global__ __launch_bounds__(256) void gemm_bt(GPair p0, GPair p1, int lda0, int lda1,
                                               int ksplit, int N, int K) {
  static_assert(WAVES_M * WAVES_N == 4, "4 waves per block");
  const GPair p = (blockIdx.y == 0) ? p0 : p1;
  constexpr int BK = 64;
  constexpr int LD = BK + 8;  // +8 shorts (16B) pad: rows shift 4 banks -> <=2-way conflict
  __shared__ unsigned short a_lds[128 * LD];
  __shared__ unsigned short w_lds[BN * LD];

  const int tid = threadIdx.x;
  const int wave = tid >> 6;
  const int lane = tid & 63;
  const int quad = lane >> 4;
  const int l16 = lane & 15;
  const int n0 = blockIdx.x * BN;

  constexpr int WM = 128 / WAVES_M;
  constexpr int WN = BN / WAVES_N;
  constexpr int MT = WM / 16;
  constexpr int NT = WN / 16;
  const int wm = (wave / WAVES_N) * WM;
  const int wn = (wave % WAVES_N) * WN;

  f32x4 acc[MT][NT] = {};

  for (int k0 = 0; k0 < K; k0 += BK) {
    // stage A tile: 128 x 64 fp32 -> bf16 LDS (2048 float4 / 256 threads)
#pragma unroll
    for (int i = 0; i < 8; ++i) {
      int idx = tid + i * 256;
      int m = idx >> 4;
      int kq = idx & 15;
      int kk = k0 + kq * 4;
      const float* src;
      if (p.A1 != nullptr && kk >= ksplit) {
        src = p.A1 + (size_t)m * lda1 + (kk - ksplit);
      } else {
        int r = (p.rows != nullptr) ? p.rows[m] : m;
        src = p.A + (size_t)r * lda0 + kk;
      }
      f32x4 v = *(const f32x4*)src;
      uint2 pk;
      pk.x = (unsigned)f2bf_bits(v.x) | ((unsigned)f2bf_bits(v.y) << 16);
      pk.y = (unsigned)f2bf_bits(v.z) | ((unsigned)f2bf_bits(v.w) << 16);
      *(uint2*)&a_lds[m * LD + kq * 4] = pk;
    }
    // stage W tile: BN x 64
#pragma unroll
    for (int i = 0; i < (BN * 16) / 256; ++i) {
      int idx = tid + i * 256;
      int n = idx >> 4;
      int kq = idx & 15;
      f32x4 v = *(const f32x4*)(p.W + (size_t)(n0 + n) * K + k0 + kq * 4);
      uint2 pk;
      pk.x = (unsigned)f2bf_bits(v.x) | ((unsigned)f2bf_bits(v.y) << 16);
      pk.y = (unsigned)f2bf_bits(v.z) | ((unsigned)f2bf_bits(v.w) << 16);
      *(uint2*)&w_lds[n * LD + kq * 4] = pk;
    }
    __syncthreads();
#pragma unroll
    for (int kh = 0; kh < 2; ++kh) {
      const int kb = kh * 32 + quad * 8;
      bf16x8 af[MT];
      bf16x8 wf[NT];
#pragma unroll
      for (int mt = 0; mt < MT; ++mt)
        af[mt] = __builtin_bit_cast(bf16x8, *(const short8*)&a_lds[(wm + mt * 16 + l16) * LD + kb]);
#pragma unroll
      for (int nt = 0; nt < NT; ++nt)
        wf[nt] = __builtin_bit_cast(bf16x8, *(const short8*)&w_lds[(wn + nt * 16 + l16) * LD + kb]);
#pragma unroll
      for (int mt = 0; mt < MT; ++mt)
#pragma unroll
        for (int nt = 0; nt < NT; ++nt)
          acc[mt][nt] = __builtin_amdgcn_mfma_f32_16x16x32_bf16(af[mt], wf[nt], acc[mt][nt], 0, 0, 0);
    }
    __syncthreads();
  }

  // epilogue: D layout col = lane&15, row = quad*4 + reg  [m89-verified]
#pragma unroll
  for (int mt = 0; mt < MT; ++mt)
#pragma unroll
    for (int nt = 0; nt < NT; ++nt) {
      int n = n0 + wn + nt * 16 + l16;
      float bv = p.bias[n];
#pragma unroll
      for (int r = 0; r < 4; ++r) {
        int m = wm + mt * 16 + quad * 4 + r;
        float val = acc[mt][nt][r] + bv;
        if (TANH) val = tanhf(val);
        p.C[(size_t)m * N + n] = val;
      }
    }
}

// ---------------------------------------------------------------------------
// GRU gate combine: h' = (1-z)*n + z*h  with r,z,n gate order (PyTorch)
// ---------------------------------------------------------------------------
__global__ __launch_bounds__(256) void gru_gate(const float* __restrict__ gi,
                                                const float* __restrict__ gh,
                                                const float* __restrict__ h_prev,
                                                float* __restrict__ h_out) {
  int idx = blockIdx.x * 256 + threadIdx.x;  // 0 .. 128*1024
  int b = idx >> 10;
  int j = idx & 1023;
  const float* gib = gi + (size_t)b * 3072;
  const float* ghb = gh + (size_t)b * 3072;
  float ir = gib[j], iz = gib[1024 + j], in_ = gib[2048 + j];
  float hr = ghb[j], hz = ghb[1024 + j], hn = ghb[2048 + j];
  float r = 1.f / (1.f + expf(-(ir + hr)));
  float z = 1.f / (1.f + expf(-(iz + hz)));
  float n = tanhf(in_ + r * hn);
  h_out[idx] = (1.f - z) * n + z * h_prev[idx];
}

// ---------------------------------------------------------------------------
// u2[e] = sum_h v[h] * W_attn[h, H+e]   (only the encoder half of W_attn
// matters: the h-half and b_attn shift all scores equally -> softmax-invariant)
// grid = 4 e-blocks x 32 h-chunks, atomicAdd into zeroed u2
// ---------------------------------------------------------------------------
__global__ __launch_bounds__(256) void u2_kernel(const float* __restrict__ W_attn,
                                                 const float* __restrict__ v,
                                                 float* __restrict__ u2) {
  int eb = blockIdx.x & 3;
  int hc = blockIdx.x >> 2;
  int e = eb * 256 + threadIdx.x;
  float acc = 0.f;
  int h0 = hc * 32;
#pragma unroll 4
  for (int h = h0; h < h0 + 32; ++h)
    acc += v[h] * W_attn[(size_t)h * 2048 + 1024 + e];
  atomicAdd(u2 + e, acc);
}

// ---------------------------------------------------------------------------
// scores_t[b,s] = enc[s,b,:] . u2    (fp32, memory-streaming GEMV)
// 512 blocks x 4 waves; each wave handles 16 rows; lane-parallel dot + shuffle
// ---------------------------------------------------------------------------
__global__ __launch_bounds__(256) void scores_kernel(const float* __restrict__ enc,
                                                     const float* __restrict__ u2,
                                                     float* __restrict__ scores_t) {
  int wave = threadIdx.x >> 6;
  int lane = threadIdx.x & 63;
  const f32x4* u4 = (const f32x4*)u2;
  f32x4 uv[4];
#pragma unroll
  for (int p = 0; p < 4; ++p) uv[p] = u4[lane + p * 64];

  int row0 = blockIdx.x * 64 + wave * 16;
  for (int i = 0; i < 16; ++i) {
    int row = row0 + i;  // row = s*128 + b  (enc is [S,B,H])
    const f32x4* e4 = (const f32x4*)(enc + (size_t)row * 1024);
    float acc = 0.f;
#pragma unroll
    for (int p = 0; p < 4; ++p) {
      f32x4 ev = e4[lane + p * 64];
      acc += ev.x * uv[p].x + ev.y * uv[p].y + ev.z * uv[p].z + ev.w * uv[p].w;
    }
#pragma unroll
    for (int off = 32; off > 0; off >>= 1) acc += __shfl_down(acc, off, 64);
    if (lane == 0) {
      int s = row >> 7;
      int b = row & 127;
      scores_t[b * 256 + s] = acc;
    }
  }
}

// ---------------------------------------------------------------------------
// softmax over s (per b) + context[b,h] = sum_s attn[b,s]*enc[s,b,h]
// grid = 128 b x 4 h-chunks (softmax replicated per chunk; chunk 0 writes attn)
// ---------------------------------------------------------------------------
__global__ __launch_bounds__(256) void context_kernel(const float* __restrict__ enc,
                                                      const float* __restrict__ scores_t,
                                                      float* __restrict__ attn_out,
                                                      float* __restrict__ ctx) {
  __shared__ float sm[256];
  __shared__ float red[256];
  int b = blockIdx.x >> 2;
  int hc = blockIdx.x & 3;
  int t = threadIdx.x;

  float sc = scores_t[b * 256 + t];
  red[t] = sc;
  __syncthreads();
  for (int off = 128; off > 0; off >>= 1) {
    if (t < off) red[t] = fmaxf(red[t], red[t + off]);
    __syncthreads();
  }
  float mx = red[0];
  __syncthreads();
  float e = expf(sc - mx);
  red[t] = e;
  __syncthreads();
  for (int off = 128; off > 0; off >>= 1) {
    if (t < off) red[t] += red[t + off];
    __syncthreads();
  }
  float aw = e / red[0];
  sm[t] = aw;
  if (hc == 0) attn_out[b * 256 + t] = aw;
  __syncthreads();

  int h = hc * 256 + t;
  const float* ep = enc + (size_t)b * 1024 + h;
  float a0 = 0.f, a1 = 0.f, a2 = 0.f, a3 = 0.f;
  for (int s = 0; s < 256; s += 4) {
    a0 += sm[s + 0] * ep[(size_t)(s + 0) * 131072];
    a1 += sm[s + 1] * ep[(size_t)(s + 1) * 131072];
    a2 += sm[s + 2] * ep[(size_t)(s + 2) * 131072];
    a3 += sm[s + 3] * ep[(size_t)(s + 3) * 131072];
  }
  ctx[b * 1024 + h] = (a0 + a1) + (a2 + a3);
}

// ---------------------------------------------------------------------------
extern "C" void kernel_launch(void* const* d_in, const int* in_sizes, int n_in,
                              void* d_out_, int out_size, void* d_ws, size_t ws_size,
                              hipStream_t stream) {
  const int* ids = (const int*)d_in[0];
  const float* hidden = (const float*)d_in[1];
  const float* enc = (const float*)d_in[2];
  const float* embed = (const float*)d_in[3];
  const float* W_attn = (const float*)d_in[4];
  // d_in[5] = b_attn: softmax-shift-invariant, unused
  const float* v = (const float*)d_in[6];
  const float* w_ih0 = (const float*)d_in[7];
  const float* w_hh0 = (const float*)d_in[8];
  const float* b_ih0 = (const float*)d_in[9];
  const float* b_hh0 = (const float*)d_in[10];
  const float* w_ih1 = (const float*)d_in[11];
  const float* w_hh1 = (const float*)d_in[12];
  const float* b_ih1 = (const float*)d_in[13];
  const float* b_hh1 = (const float*)d_in[14];
  const float* W_cat = (const float*)d_in[15];
  const float* b_cat = (const float*)d_in[16];
  const float* W_out = (const float*)d_in[17];
  const float* b_out = (const float*)d_in[18];

  float* out = (float*)d_out_;
  float* ws = (float*)d_ws;

  // d_out layout: output[128,32000] | new_hidden[2,128,1024] | attn[128,1,256]
  float* h0 = out + 4096000;
  float* h1 = out + 4227072;
  float* attn = out + 4358144;

  // workspace layout (floats)
  float* gi = ws;                // 128*3072
  float* gh = ws + 393216;       // 128*3072
  float* u2 = ws + 786432;       // 1024
  float* ctx = ws + 787456;      // 128*1024
  float* cat = ws + 918528;      // 128*1024
  float* sct = ws + 1049600;     // 128*256 (scores transposed [b,s])

  const int NEVER = 1 << 30;

  // ---- attention path (independent of GRU until concat) ----
  hipMemsetAsync(u2, 0, 1024 * sizeof(float), stream);
  u2_kernel<<<128, 256, 0, stream>>>(W_attn, v, u2);
  scores_kernel<<<512, 256, 0, stream>>>(enc, u2, sct);
  context_kernel<<<512, 256, 0, stream>>>(enc, sct, attn, ctx);

  // ---- GRU layer 0 (embedding gathered in-GEMM via rows=ids) ----
  {
    GPair pi{embed, ids, nullptr, w_ih0, b_ih0, gi};
    GPair ph{hidden, nullptr, nullptr, w_hh0, b_hh0, gh};
    gemm_bt<32, 2, 2, false><<<dim3(3072 / 32, 2), 256, 0, stream>>>(pi, ph, 1024, 0, NEVER, 3072, 1024);
  }
  gru_gate<<<512, 256, 0, stream>>>(gi, gh, hidden, h0);

  // ---- GRU layer 1 ----
  {
    GPair pi{h0, nullptr, nullptr, w_ih1, b_ih1, gi};
    GPair ph{hidden + 131072, nullptr, nullptr, w_hh1, b_hh1, gh};
    gemm_bt<32, 2, 2, false><<<dim3(3072 / 32, 2), 256, 0, stream>>>(pi, ph, 1024, 0, NEVER, 3072, 1024);
  }
  gru_gate<<<512, 256, 0, stream>>>(gi, gh, hidden + 131072, h1);

  // ---- concat_out = tanh([h1, context] @ W_concat^T + b_concat) ----
  {
    GPair pc{h1, nullptr, ctx, W_cat, b_cat, cat};
    gemm_bt<16, 4, 1, true><<<dim3(1024 / 16, 1), 256, 0, stream>>>(pc, pc, 1024, 1024, 1024, 1024, 2048);
  }

  // ---- output = concat_out @ W_out^T + b_out ----
  {
    GPair po{cat, nullptr, nullptr, W_out, b_out, out};
    gemm_bt<64, 2, 2, false><<<dim3(32000 / 64, 1), 256, 0, stream>>>(po, po, 1024, 0, NEVER, 32000, 1024);
  }
}

// Round 2
// 471.987 us; speedup vs baseline: 1.6085x; 1.6085x over previous
//
#include <hip/hip_runtime.h>
#include <cstdint>
#include <cstddef>

typedef __attribute__((ext_vector_type(4))) float f32x4;
typedef __attribute__((ext_vector_type(8))) __bf16 bf16x8;
typedef __attribute__((ext_vector_type(8))) short short8;

__device__ __forceinline__ unsigned short f2bf(float f) {
  unsigned u = __builtin_bit_cast(unsigned, f);
  u += 0x7FFFu + ((u >> 16) & 1u);  // RNE
  return (unsigned short)(u >> 16);
}
__device__ __forceinline__ unsigned pack2(float a, float b) {
  return (unsigned)f2bf(a) | ((unsigned)f2bf(b) << 16);
}

// async 16B global->LDS (wave-uniform base + lane*16; our per-lane addrs satisfy this)
__device__ __forceinline__ void async16(const void* g, void* l) {
  __builtin_amdgcn_global_load_lds((const __attribute__((address_space(1))) unsigned int*)g,
                                   (__attribute__((address_space(3))) unsigned int*)l, 16, 0, 0);
}

// ---------------------------------------------------------------------------
// GEMM: C[128,N](fp32, +bias on kseg0) = A[128,K](bf16) @ W[N,K](fp32)^T
// A staged via global_load_lds into XOR-swizzled LDS (cc = c ^ (r&7), 16B chunks).
// W loaded to regs one tile ahead (latency cover), converted, ds_written.
// blockIdx.y: arg pair (GRU gi/gh in one launch). blockIdx.z: K-split segment.
// ---------------------------------------------------------------------------
struct GemmArgs {
  const unsigned short* A;  // bf16 [128, lda]
  const float* W;           // fp32 [N, ldw]
  const float* bias;        // [N]
  float* C;                 // fp32 [128, N] at C + kseg*seg_stride
};

template <int BN, int WAVES_M, int WAVES_N>
__global__ __launch_bounds__(256, 4) void gemm_bt(GemmArgs g0, GemmArgs g1, int lda, int ldw,
                                                  int N, int Kseg, int seg_stride) {
  constexpr int WM = 128 / WAVES_M, WN = BN / WAVES_N;
  constexpr int MT = WM / 16, NT = WN / 16;
  __shared__ unsigned short a_lds[2][128 * 64];
  __shared__ unsigned short w_lds[2][BN * 64];

  const GemmArgs g = (blockIdx.y == 0) ? g0 : g1;
  const int kbase = blockIdx.z * Kseg;
  const int tid = threadIdx.x;
  const int wave = tid >> 6, lane = tid & 63;
  const int quad = lane >> 4, l16 = lane & 15;
  const int n0 = blockIdx.x * BN;
  const int wm = (wave / WAVES_N) * WM, wn = (wave % WAVES_N) * WN;
  const int niter = Kseg >> 6;

  f32x4 wv[2];

  auto stageA = [&](int k0, int buf) {
#pragma unroll
    for (int i = 0; i < 4; ++i) {
      int chunk = (wave * 4 + i) * 64 + lane;          // 1024 chunks = 128 rows x 8
      int r = chunk >> 3;
      int c = (chunk & 7) ^ (r & 7);                   // logical 16B-chunk for this slot
      async16(g.A + (size_t)r * lda + (k0 + c * 8), &a_lds[buf][chunk * 8]);
    }
  };
  auto loadW = [&](int k0) {
    if constexpr (BN == 32) {
      const float* p = g.W + (size_t)(n0 + (tid >> 3)) * ldw + k0 + (tid & 7) * 8;
      wv[0] = *(const f32x4*)p;
      wv[1] = *(const f32x4*)(p + 4);
    } else {
      const float* p = g.W + (size_t)(n0 + (tid >> 4)) * ldw + k0 + ((tid >> 1) & 7) * 8 + (tid & 1) * 4;
      wv[0] = *(const f32x4*)p;
    }
  };
  auto writeW = [&](int buf) {
    if constexpr (BN == 32) {
      int wr = tid >> 3, wc = tid & 7;
      uint4 pk{pack2(wv[0].x, wv[0].y), pack2(wv[0].z, wv[0].w),
               pack2(wv[1].x, wv[1].y), pack2(wv[1].z, wv[1].w)};
      *(uint4*)&w_lds[buf][(wr * 8 + (wc ^ (wr & 7))) * 8] = pk;
    } else {
      int wr = tid >> 4, wc = (tid >> 1) & 7, half = tid & 1;
      uint2 pk{pack2(wv[0].x, wv[0].y), pack2(wv[0].z, wv[0].w)};
      *(uint2*)&w_lds[buf][(wr * 8 + (wc ^ (wr & 7))) * 8 + half * 4] = pk;
    }
  };

  f32x4 acc[MT][NT] = {};

  stageA(kbase, 0);
  loadW(kbase);
  writeW(0);
  __syncthreads();

  for (int ki = 0; ki < niter; ++ki) {
    const int cur = ki & 1;
    const bool more = (ki + 1 < niter);
    if (more) {
      stageA(kbase + (ki + 1) * 64, cur ^ 1);   // async into other buffer
      loadW(kbase + (ki + 1) * 64);             // in flight across MFMA phase
    }
#pragma unroll
    for (int kh = 0; kh < 2; ++kh) {
      const int c = kh * 4 + quad;
      bf16x8 af[MT], wf[NT];
#pragma unroll
      for (int mt = 0; mt < MT; ++mt) {
        int m = wm + mt * 16 + l16;
        af[mt] = __builtin_bit_cast(bf16x8, *(const short8*)&a_lds[cur][(m * 8 + (c ^ (m & 7))) * 8]);
      }
#pragma unroll
      for (int nt = 0; nt < NT; ++nt) {
        int n = wn + nt * 16 + l16;
        wf[nt] = __builtin_bit_cast(bf16x8, *(const short8*)&w_lds[cur][(n * 8 + (c ^ (n & 7))) * 8]);
      }
#pragma unroll
      for (int mt = 0; mt < MT; ++mt)
#pragma unroll
        for (int nt = 0; nt < NT; ++nt)
          acc[mt][nt] = __builtin_amdgcn_mfma_f32_16x16x32_bf16(af[mt], wf[nt], acc[mt][nt], 0, 0, 0);
    }
    if (more) writeW(cur ^ 1);
    __syncthreads();
  }

  float* C = g.C + (size_t)blockIdx.z * seg_stride;
#pragma unroll
  for (int mt = 0; mt < MT; ++mt)
#pragma unroll
    for (int nt = 0; nt < NT; ++nt) {
      int n = n0 + wn + nt * 16 + l16;
      float bv = (blockIdx.z == 0) ? g.bias[n] : 0.f;
#pragma unroll
      for (int r = 0; r < 4; ++r) {
        int m = wm + mt * 16 + quad * 4 + r;
        C[(size_t)m * N + n] = acc[mt][nt][r] + bv;
      }
    }
}

// ---------------------------------------------------------------------------
// prep: bf16 copies of embed[ids] (A0), hidden[0] (Hh0), hidden[1] (Hh1)
// ---------------------------------------------------------------------------
__global__ __launch_bounds__(256) void prep_kernel(const int* __restrict__ ids,
                                                   const float* __restrict__ hidden,
                                                   const float* __restrict__ embed,
                                                   unsigned short* A0, unsigned short* Hh0,
                                                   unsigned short* Hh1) {
  int job = blockIdx.x >> 7, m = blockIdx.x & 127, t = threadIdx.x;
  const float* src;
  unsigned short* dst;
  if (job == 0) { src = embed + (size_t)ids[m] * 1024; dst = A0; }
  else if (job == 1) { src = hidden + (size_t)m * 1024; dst = Hh0; }
  else { src = hidden + 131072 + (size_t)m * 1024; dst = Hh1; }
  f32x4 v = ((const f32x4*)src)[t];
  uint2 pk{pack2(v.x, v.y), pack2(v.z, v.w)};
  *(uint2*)(dst + (size_t)m * 1024 + t * 4) = pk;
}

// ---------------------------------------------------------------------------
// u2[e] = sum_h v[h] * W_attn[h, 1024+e]  (h-half + b_attn are softmax-invariant)
// ---------------------------------------------------------------------------
__global__ __launch_bounds__(256) void u2_kernel(const float* __restrict__ W_attn,
                                                 const float* __restrict__ v,
                                                 float* __restrict__ u2) {
  int eb = blockIdx.x & 3, hc = blockIdx.x >> 2;
  int e = eb * 256 + threadIdx.x;
  float acc = 0.f;
  int h0 = hc * 32;
#pragma unroll 4
  for (int h = h0; h < h0 + 32; ++h) acc += v[h] * W_attn[(size_t)h * 2048 + 1024 + e];
  atomicAdd(u2 + e, acc);
}

// ---------------------------------------------------------------------------
// scores_t[b,s] = enc[s,b,:] . u2 ; 8192 waves x 4 rows, 16 loads batched/wave
// ---------------------------------------------------------------------------
__global__ __launch_bounds__(256) void scores_kernel(const float* __restrict__ enc,
                                                     const float* __restrict__ u2,
                                                     float* __restrict__ sct) {
  int wave = threadIdx.x >> 6, lane = threadIdx.x & 63;
  const f32x4* u4 = (const f32x4*)u2;
  f32x4 uv[4];
#pragma unroll
  for (int p = 0; p < 4; ++p) uv[p] = u4[p * 64 + lane];
  int row0 = (blockIdx.x * 4 + wave) * 4;
  const f32x4* base = (const f32x4*)enc;
  f32x4 ev[4][4];
#pragma unroll
  for (int r = 0; r < 4; ++r)
#pragma unroll
    for (int p = 0; p < 4; ++p) ev[r][p] = base[(size_t)(row0 + r) * 256 + p * 64 + lane];
  float a[4];
#pragma unroll
  for (int r = 0; r < 4; ++r) {
    float s = 0.f;
#pragma unroll
    for (int p = 0; p < 4; ++p)
      s += ev[r][p].x * uv[p].x + ev[r][p].y * uv[p].y + ev[r][p].z * uv[p].z + ev[r][p].w * uv[p].w;
    a[r] = s;
  }
#pragma unroll
  for (int r = 0; r < 4; ++r)
#pragma unroll
    for (int off = 32; off > 0; off >>= 1) a[r] += __shfl_down(a[r], off, 64);
  if (lane == 0) {
#pragma unroll
    for (int r = 0; r < 4; ++r) {
      int row = row0 + r;
      sct[(row & 127) * 256 + (row >> 7)] = a[r];
    }
  }
}

// ---------------------------------------------------------------------------
// softmax over s per b; writes attn (final output 3, also context input)
// ---------------------------------------------------------------------------
__global__ __launch_bounds__(256) void softmax_kernel(const float* __restrict__ sct,
                                                      float* __restrict__ attn) {
  __shared__ float wmax[4], wsum[4];
  int b = blockIdx.x, t = threadIdx.x;
  int wave = t >> 6, lane = t & 63;
  float sc = sct[b * 256 + t];
  float m = sc;
#pragma unroll
  for (int off = 32; off > 0; off >>= 1) m = fmaxf(m, __shfl_xor(m, off, 64));
  if (lane == 0) wmax[wave] = m;
  __syncthreads();
  float m4 = fmaxf(fmaxf(wmax[0], wmax[1]), fmaxf(wmax[2], wmax[3]));
  float e = __expf(sc - m4);
  float s = e;
#pragma unroll
  for (int off = 32; off > 0; off >>= 1) s += __shfl_xor(s, off, 64);
  if (lane == 0) wsum[wave] = s;
  __syncthreads();
  float tot = (wsum[0] + wsum[1]) + (wsum[2] + wsum[3]);
  attn[b * 256 + t] = e / tot;
}

// ---------------------------------------------------------------------------
// context[b,h] = sum_s attn[b,s]*enc[s,b,h] -> bf16 into catin[:,1024+h]
// ---------------------------------------------------------------------------
__global__ __launch_bounds__(256) void context_kernel(const float* __restrict__ enc,
                                                      const float* __restrict__ attn,
                                                      unsigned short* __restrict__ catin) {
  __shared__ float sm[256];
  int b = blockIdx.x >> 2, hc = blockIdx.x & 3;
  int t = threadIdx.x;
  sm[t] = attn[b * 256 + t];
  __syncthreads();
  int h = hc * 256 + t;
  const float* ep = enc + (size_t)b * 1024 + h;
  float a[16];
#pragma unroll
  for (int i = 0; i < 16; ++i) a[i] = 0.f;
  for (int s0 = 0; s0 < 256; s0 += 16)
#pragma unroll
    for (int i = 0; i < 16; ++i) a[i] += sm[s0 + i] * ep[(size_t)(s0 + i) * 131072];
  float tot = 0.f;
#pragma unroll
  for (int i = 0; i < 16; ++i) tot += a[i];
  catin[(size_t)b * 2048 + 1024 + h] = f2bf(tot);
}

// ---------------------------------------------------------------------------
// GRU gate: sums the 2 K-split partials of gi/gh; writes h fp32 + bf16 copy
// ---------------------------------------------------------------------------
__global__ __launch_bounds__(256) void gru_gate(const float* __restrict__ gi,
                                                const float* __restrict__ gh,
                                                const float* __restrict__ h_prev,
                                                float* __restrict__ h_out,
                                                unsigned short* __restrict__ h_bf, int bf_ld) {
  constexpr int SEG = 393216;
  int b = blockIdx.x, j = threadIdx.x * 4;
  const float* gib = gi + (size_t)b * 3072;
  const float* ghb = gh + (size_t)b * 3072;
  f32x4 ir = *(const f32x4*)(gib + j) + *(const f32x4*)(gib + SEG + j);
  f32x4 iz = *(const f32x4*)(gib + 1024 + j) + *(const f32x4*)(gib + SEG + 1024 + j);
  f32x4 in_ = *(const f32x4*)(gib + 2048 + j) + *(const f32x4*)(gib + SEG + 2048 + j);
  f32x4 hr = *(const f32x4*)(ghb + j) + *(const f32x4*)(ghb + SEG + j);
  f32x4 hz = *(const f32x4*)(ghb + 1024 + j) + *(const f32x4*)(ghb + SEG + 1024 + j);
  f32x4 hn = *(const f32x4*)(ghb + 2048 + j) + *(const f32x4*)(ghb + SEG + 2048 + j);
  f32x4 hp = *(const f32x4*)(h_prev + (size_t)b * 1024 + j);
  f32x4 ho;
#pragma unroll
  for (int c = 0; c < 4; ++c) {
    float r = 1.f / (1.f + __expf(-(ir[c] + hr[c])));
    float z = 1.f / (1.f + __expf(-(iz[c] + hz[c])));
    float n = tanhf(in_[c] + r * hn[c]);
    ho[c] = (1.f - z) * n + z * hp[c];
  }
  *(f32x4*)(h_out + (size_t)b * 1024 + j) = ho;
  uint2 pk{pack2(ho.x, ho.y), pack2(ho.z, ho.w)};
  *(uint2*)(h_bf + (size_t)b * bf_ld + j) = pk;
}

// ---------------------------------------------------------------------------
// cat_fix: sum 4 K-split partials (bias already in seg0), tanh, bf16
// ---------------------------------------------------------------------------
__global__ __launch_bounds__(256) void cat_fix(const float* __restrict__ part,
                                               unsigned short* __restrict__ catbf) {
  int m = blockIdx.x, j = threadIdx.x * 4;
  const float* p = part + (size_t)m * 1024 + j;
  f32x4 s = *(const f32x4*)p + *(const f32x4*)(p + 131072) + *(const f32x4*)(p + 262144) +
            *(const f32x4*)(p + 393216);
  f32x4 o;
#pragma unroll
  for (int c = 0; c < 4; ++c) o[c] = tanhf(s[c]);
  uint2 pk{pack2(o.x, o.y), pack2(o.z, o.w)};
  *(uint2*)(catbf + (size_t)m * 1024 + j) = pk;
}

// ---------------------------------------------------------------------------
extern "C" void kernel_launch(void* const* d_in, const int* in_sizes, int n_in,
                              void* d_out_, int out_size, void* d_ws, size_t ws_size,
                              hipStream_t stream) {
  const int* ids = (const int*)d_in[0];
  const float* hidden = (const float*)d_in[1];
  const float* enc = (const float*)d_in[2];
  const float* embed = (const float*)d_in[3];
  const float* W_attn = (const float*)d_in[4];
  const float* v = (const float*)d_in[6];
  const float* w_ih0 = (const float*)d_in[7];
  const float* w_hh0 = (const float*)d_in[8];
  const float* b_ih0 = (const float*)d_in[9];
  const float* b_hh0 = (const float*)d_in[10];
  const float* w_ih1 = (const float*)d_in[11];
  const float* w_hh1 = (const float*)d_in[12];
  const float* b_ih1 = (const float*)d_in[13];
  const float* b_hh1 = (const float*)d_in[14];
  const float* W_cat = (const float*)d_in[15];
  const float* b_cat = (const float*)d_in[16];
  const float* W_out = (const float*)d_in[17];
  const float* b_out = (const float*)d_in[18];

  float* out = (float*)d_out_;
  float* h0 = out + 4096000;
  float* h1 = out + 4227072;
  float* attn = out + 4358144;

  float* ws = (float*)d_ws;
  float* gi = ws;                    // 2 x 393216
  float* gh = ws + 786432;           // 2 x 393216
  float* u2 = ws + 1572864;          // 1024
  float* sct = ws + 1573888;         // 32768
  float* catp = ws + 1606656;        // 4 x 131072
  unsigned short* bfb = (unsigned short*)(ws + 2130944);
  unsigned short* A0 = bfb;              // 131072
  unsigned short* Hh0 = bfb + 131072;
  unsigned short* Hh1 = bfb + 262144;
  unsigned short* h0bf = bfb + 393216;
  unsigned short* catin = bfb + 524288;  // 128 x 2048
  unsigned short* catbf = bfb + 786432;  // 128 x 1024

  // attention path
  hipMemsetAsync(u2, 0, 1024 * sizeof(float), stream);
  prep_kernel<<<384, 256, 0, stream>>>(ids, hidden, embed, A0, Hh0, Hh1);
  u2_kernel<<<128, 256, 0, stream>>>(W_attn, v, u2);
  scores_kernel<<<2048, 256, 0, stream>>>(enc, u2, sct);
  softmax_kernel<<<128, 256, 0, stream>>>(sct, attn);
  context_kernel<<<512, 256, 0, stream>>>(enc, attn, catin);

  // GRU layer 0
  {
    GemmArgs ai{A0, w_ih0, b_ih0, gi}, ah{Hh0, w_hh0, b_hh0, gh};
    gemm_bt<16, 4, 1><<<dim3(192, 2, 2), 256, 0, stream>>>(ai, ah, 1024, 1024, 3072, 512, 393216);
  }
  gru_gate<<<128, 256, 0, stream>>>(gi, gh, hidden, h0, h0bf, 1024);

  // GRU layer 1
  {
    GemmArgs ai{h0bf, w_ih1, b_ih1, gi}, ah{Hh1, w_hh1, b_hh1, gh};
    gemm_bt<16, 4, 1><<<dim3(192, 2, 2), 256, 0, stream>>>(ai, ah, 1024, 1024, 3072, 512, 393216);
  }
  gru_gate<<<128, 256, 0, stream>>>(gi, gh, hidden + 131072, h1, catin, 2048);

  // concat GEMM (K=2048, split-K 4) + tanh/bf16 fixup
  {
    GemmArgs ac{catin, W_cat, b_cat, catp};
    gemm_bt<16, 4, 1><<<dim3(64, 1, 4), 256, 0, stream>>>(ac, ac, 2048, 2048, 1024, 512, 131072);
  }
  cat_fix<<<128, 256, 0, stream>>>(catp, catbf);

  // output GEMM
  {
    GemmArgs ao{catbf, W_out, b_out, out};
    gemm_bt<32, 2, 2><<<dim3(1000, 1, 1), 256, 0, stream>>>(ao, ao, 1024, 1024, 32000, 1024, 0);
  }
}